// Round 8
// baseline (7080.498 us; speedup 1.0000x reference)
//
#include <hip/hip_runtime.h>

typedef unsigned short u16;
typedef unsigned int   u32;

#define SEQ    2048
#define HEADS  16
#define DM     1024
#define NBH    32      /* B*H */
#define NBS    4096    /* B*S */

__device__ __forceinline__ float b2f(u16 u) {
    u32 x = ((u32)u) << 16;
    float f;
    __builtin_memcpy(&f, &x, 4);
    return f;
}
__device__ __forceinline__ u16 f2b(float f) {
    u32 x;
    __builtin_memcpy(&x, &f, 4);
    return (u16)((x + 0x7fffu + ((x >> 16) & 1u)) >> 16);  // RNE
}

// ---------------------------------------------------------------------------
// Naive QKV projection. One block = one x-row (b,s) x 256 output cols.
// col in [0,3072): z = col>>10 selects W_Q/W_K/W_V (block-uniform).
// Writes Q/K/V as bf16 in (bh, s, d) layout.
// ---------------------------------------------------------------------------
__global__ __launch_bounds__(256) void proj_qkv(const float* __restrict__ x,
                                                const float* __restrict__ Wq,
                                                const float* __restrict__ Wk,
                                                const float* __restrict__ Wv,
                                                u16* __restrict__ Qb,
                                                u16* __restrict__ Kb,
                                                u16* __restrict__ Vb) {
    __shared__ float xr[DM];
    const int row = blockIdx.x;                       // [0,4096)
    const int col = blockIdx.y * 256 + threadIdx.x;   // [0,3072)
    for (int i = threadIdx.x; i < DM; i += 256)
        xr[i] = x[(size_t)row * DM + i];
    __syncthreads();

    const int z  = col >> 10;                         // block-uniform
    const int c1 = col & 1023;
    const float* W = (z == 0) ? Wq : (z == 1) ? Wk : Wv;

    float acc = 0.f;
    for (int k = 0; k < DM; ++k)
        acc = fmaf(xr[k], W[(size_t)k * DM + c1], acc);

    const int h = c1 >> 6, d = c1 & 63;
    const int b = row >> 11, s = row & (SEQ - 1);
    const size_t idx = (((size_t)(b * HEADS + h)) * SEQ + s) * 64 + d;
    u16 val = f2b(acc);
    if (z == 0)      Qb[idx] = val;
    else if (z == 1) Kb[idx] = val;
    else             Vb[idx] = val;
}

// ---------------------------------------------------------------------------
// RoPE for Q,K in-place on (bh,s,d) bf16; cos/sin fp32 tables (S x 32).
// token_positions == arange(SEQ). One thread per even/odd pair; 8192 blocks.
// ---------------------------------------------------------------------------
__global__ __launch_bounds__(256) void rope_qk(u16* __restrict__ Qp,
                                               u16* __restrict__ Kp,
                                               const float* __restrict__ cosT,
                                               const float* __restrict__ sinT) {
    int t = blockIdx.x * 256 + threadIdx.x;         // [0, 2^21)
    int p  = t & 31;
    int s  = (t >> 5) & (SEQ - 1);
    int hh = (t >> 16) & (HEADS - 1);
    int b  = t >> 20;

    float cv = cosT[s * 32 + p];
    float sv = sinT[s * 32 + p];

    size_t addr = (((size_t)(b * HEADS + hh)) * SEQ + s) * 64 + 2 * p;
    u32 q2 = *(const u32*)(Qp + addr);
    u32 k2 = *(const u32*)(Kp + addr);
    float qe = b2f((u16)(q2 & 0xffff)), qo = b2f((u16)(q2 >> 16));
    float ke = b2f((u16)(k2 & 0xffff)), ko = b2f((u16)(k2 >> 16));

    u32 qout = (u32)f2b(cv * qe - sv * qo) | ((u32)f2b(sv * qe + cv * qo) << 16);
    u32 kout = (u32)f2b(cv * ke - sv * ko) | ((u32)f2b(sv * ke + cv * ko) << 16);
    *(u32*)(Qp + addr) = qout;
    *(u32*)(Kp + addr) = kout;
}

// ---------------------------------------------------------------------------
// Naive causal attention with online softmax. One wave per (bh, q) row;
// lane = head dim. Per key: full-wave shfl dot, exp, rescale, accumulate V.
// Output bf16 (b, s, h*64+d).
// ---------------------------------------------------------------------------
__global__ __launch_bounds__(256) void attn_naive(const u16* __restrict__ Qb,
                                                  const u16* __restrict__ Kb,
                                                  const u16* __restrict__ Vb,
                                                  u16* __restrict__ aob) {
    const int tid  = threadIdx.x;
    const int wave = tid >> 6, lane = tid & 63;
    const int bh = blockIdx.y;
    const int q  = blockIdx.x * 4 + wave;             // [0,2048)

    const u16* Qr = Qb + ((size_t)bh * SEQ + q) * 64;
    const u16* Kr = Kb + (size_t)bh * SEQ * 64;
    const u16* Vr = Vb + (size_t)bh * SEQ * 64;

    const float qv = b2f(Qr[lane]);
    float m = -1e30f, l = 0.f, o = 0.f;

    for (int k = 0; k <= q; ++k) {
        float kv = b2f(Kr[(size_t)k * 64 + lane]);
        float pr = qv * kv;
        for (int d = 1; d < 64; d <<= 1)
            pr += __shfl_xor(pr, d);
        float s  = pr * 0.125f;                       // 1/sqrt(64)
        float mn = fmaxf(m, s);
        float al = __expf(m - mn);
        float p  = __expf(s - mn);
        float vv = b2f(Vr[(size_t)k * 64 + lane]);
        o = o * al + p * vv;
        l = l * al + p;
        m = mn;
    }

    const int b = bh >> 4, h = bh & 15;
    aob[((size_t)b * SEQ + q) * DM + h * 64 + lane] = f2b(o / l);
}

// ---------------------------------------------------------------------------
// Naive output projection: out[row][col] = sum_k ao[row][k] * W_O[k][col].
// OUTPUT IS FP32 (the reference's output dtype — harness contract).
// ---------------------------------------------------------------------------
__global__ __launch_bounds__(256) void out_proj(const u16* __restrict__ aob,
                                                const float* __restrict__ Wo,
                                                float* __restrict__ out) {
    __shared__ float ar[DM];
    const int row = blockIdx.x;                       // [0,4096)
    const int col = blockIdx.y * 256 + threadIdx.x;   // [0,1024)
    for (int i = threadIdx.x; i < DM; i += 256)
        ar[i] = b2f(aob[(size_t)row * DM + i]);
    __syncthreads();

    float acc = 0.f;
    for (int k = 0; k < DM; ++k)
        acc = fmaf(ar[k], Wo[(size_t)k * DM + col], acc);

    out[(size_t)row * DM + col] = acc;
}

// ---------------------------------------------------------------------------
extern "C" void kernel_launch(void* const* d_in, const int* in_sizes, int n_in,
                              void* d_out, int out_size, void* d_ws, size_t ws_size,
                              hipStream_t stream) {
    const float* x    = (const float*)d_in[0];   // fp32 inputs (proven R3->R5)
    const float* Wq   = (const float*)d_in[2];
    const float* Wk   = (const float*)d_in[3];
    const float* Wv   = (const float*)d_in[4];
    const float* Wo   = (const float*)d_in[5];
    const float* cosT = (const float*)d_in[6];
    const float* sinT = (const float*)d_in[7];
    float* out = (float*)d_out;                  // fp32 output (reference dtype)

    // Workspace: 16,777,216 u16 = 33.55 MB
    u16* ws  = (u16*)d_ws;
    u16* qb  = ws;                 // (bh, s, d) bf16
    u16* kb  = ws + 4194304;
    u16* vb  = ws + 8388608;       // (bh, s, d) bf16
    u16* aob = ws + 12582912;      // (b, s, h*64+d) bf16

    dim3 blk(256);
    proj_qkv<<<dim3(NBS, 12), blk, 0, stream>>>(x, Wq, Wk, Wv, qb, kb, vb);
    rope_qk<<<dim3(8192), blk, 0, stream>>>(qb, kb, cosT, sinT);
    attn_naive<<<dim3(SEQ / 4, NBH), blk, 0, stream>>>(qb, kb, vb, aob);
    out_proj<<<dim3(NBS, 4), blk, 0, stream>>>(aob, Wo, out);
}

// Round 9
// 403.075 us; speedup vs baseline: 17.5662x; 17.5662x over previous
//
#include <hip/hip_runtime.h>

typedef unsigned short u16;
typedef unsigned int   u32;
typedef __bf16  bf16x8 __attribute__((ext_vector_type(8)));
typedef float   f32x4  __attribute__((ext_vector_type(4)));

#define SEQ    2048
#define HEADS  16
#define DM     1024
#define NBH    32      /* B*H */
#define NBS    4096    /* B*S */

__device__ __forceinline__ u16 f2b(float f) {
    u32 x;
    __builtin_memcpy(&x, &f, 4);
    return (u16)((x + 0x7fffu + ((x >> 16) & 1u)) >> 16);  // RNE
}

__device__ __forceinline__ bf16x8 ld_bf8(const u16* p) {
    return *(const bf16x8*)p;
}
__device__ __forceinline__ bf16x8 ld_f32x8_cvt(const float* p) {
    f32x4 a = *(const f32x4*)p;
    f32x4 b = *(const f32x4*)(p + 4);
    bf16x8 r;
    r[0] = (__bf16)a[0]; r[1] = (__bf16)a[1]; r[2] = (__bf16)a[2]; r[3] = (__bf16)a[3];
    r[4] = (__bf16)b[0]; r[5] = (__bf16)b[1]; r[6] = (__bf16)b[2]; r[7] = (__bf16)b[3];
    return r;
}

// ---------------------------------------------------------------------------
// Transpose + fp32->bf16 of W_Q/W_K/W_V: (k,n) -> WqkvT[z*1024 + n][k].
// ---------------------------------------------------------------------------
__global__ __launch_bounds__(256) void transpose_wqkv(const float* __restrict__ Wq,
                                                      const float* __restrict__ Wk,
                                                      const float* __restrict__ Wv,
                                                      u16* __restrict__ WqkvT) {
    __shared__ u16 tile[64][65];
    const int z  = blockIdx.z;
    const float* src = (z == 0) ? Wq : (z == 1) ? Wk : Wv;
    const int k0 = blockIdx.x * 64, n0 = blockIdx.y * 64;
    const int tid = threadIdx.x;
    for (int i = 0; i < 16; ++i) {
        int e = i * 256 + tid;
        int r = e >> 6, c = e & 63;
        tile[r][c] = f2b(src[(size_t)(k0 + r) * DM + n0 + c]);
    }
    __syncthreads();
    u16* dst = WqkvT + (size_t)z * DM * DM;
    for (int i = 0; i < 16; ++i) {
        int e = i * 256 + tid;
        int r = e >> 6, c = e & 63;
        dst[(size_t)(n0 + r) * DM + k0 + c] = tile[c][r];
    }
}

// W_O (k,n) fp32 -> WoT[n][k] bf16. Launched AFTER flash (overlays dead vt).
__global__ __launch_bounds__(256) void transpose_wo(const float* __restrict__ Wo,
                                                    u16* __restrict__ WoT) {
    __shared__ u16 tile[64][65];
    const int k0 = blockIdx.x * 64, n0 = blockIdx.y * 64;
    const int tid = threadIdx.x;
    for (int i = 0; i < 16; ++i) {
        int e = i * 256 + tid;
        int r = e >> 6, c = e & 63;
        tile[r][c] = f2b(Wo[(size_t)(k0 + r) * DM + n0 + c]);
    }
    __syncthreads();
    for (int i = 0; i < 16; ++i) {
        int e = i * 256 + tid;
        int r = e >> 6, c = e & 63;
        WoT[(size_t)(n0 + r) * DM + k0 + c] = tile[c][r];
    }
}

// ---------------------------------------------------------------------------
// Shared GEMM body: 128x128 tile, BK=64, VGPR-mediated staging,
// 4 waves 2x2, 4x4 16x16x32 MFMA tiles per wave. acc[][] left for epilogue.
// ---------------------------------------------------------------------------
#define GEMM_BODY(A_EXPR, B_EXPR, K)                                                \
    __shared__ __attribute__((aligned(16))) __bf16 As[128 * 64];                    \
    __shared__ __attribute__((aligned(16))) __bf16 Bs[128 * 64];                    \
    const int tid  = threadIdx.x;                                                   \
    const int wave = tid >> 6, lane = tid & 63;                                     \
    const int quad = lane >> 4, col = lane & 15;                                    \
    const int wm = wave >> 1, wn = wave & 1;                                        \
    const int m0 = blockIdx.x * 128, n0 = blockIdx.y * 128;                         \
    const int srow = tid >> 3;            /* 0..31 */                               \
    const int scol = (tid & 7) * 8;       /* 0..56 */                               \
    f32x4 zero = {0.f, 0.f, 0.f, 0.f};                                              \
    f32x4 acc[4][4];                                                                \
    for (int i = 0; i < 4; ++i)                                                     \
        for (int j = 0; j < 4; ++j) acc[i][j] = zero;                               \
    for (int k0 = 0; k0 < (K); k0 += 64) {                                          \
        bf16x8 av[4], bv[4];                                                        \
        for (int p = 0; p < 4; ++p) {                                               \
            int row = p * 32 + srow;                                                \
            av[p] = A_EXPR;                                                         \
            bv[p] = B_EXPR;                                                         \
        }                                                                           \
        __syncthreads();                                                            \
        for (int p = 0; p < 4; ++p) {                                               \
            int row = p * 32 + srow;                                                \
            *(bf16x8*)&As[row * 64 + scol] = av[p];                                 \
            *(bf16x8*)&Bs[row * 64 + scol] = bv[p];                                 \
        }                                                                           \
        __syncthreads();                                                            \
        for (int ks = 0; ks < 2; ++ks) {                                            \
            bf16x8 af[4], bfr[4];                                                   \
            for (int mt = 0; mt < 4; ++mt)                                          \
                af[mt] = *(const bf16x8*)&As[(wm * 64 + mt * 16 + col) * 64 +       \
                                             ks * 32 + quad * 8];                   \
            for (int nt = 0; nt < 4; ++nt)                                          \
                bfr[nt] = *(const bf16x8*)&Bs[(wn * 64 + nt * 16 + col) * 64 +      \
                                              ks * 32 + quad * 8];                  \
            for (int mt = 0; mt < 4; ++mt)                                          \
                for (int nt = 0; nt < 4; ++nt)                                      \
                    acc[mt][nt] = __builtin_amdgcn_mfma_f32_16x16x32_bf16(          \
                        af[mt], bfr[nt], acc[mt][nt], 0, 0, 0);                     \
        }                                                                           \
    }

// ---------------------------------------------------------------------------
// Fused QKV GEMM: x(4096x1024 fp32) x WqkvT(3072x1024 bf16)^T.
// Staging converts A fp32->bf16 in-register. Epilogue scatters to
// Qp (bh,s,d), Kp (bh,s,d), Vt (bh,d,s).
// ---------------------------------------------------------------------------
__global__ __launch_bounds__(256) void gemm_qkv(const float* __restrict__ Af,
                                                const u16* __restrict__ Bt,
                                                u16* __restrict__ Qp,
                                                u16* __restrict__ Kp,
                                                u16* __restrict__ Vt) {
    GEMM_BODY(ld_f32x8_cvt(Af + (size_t)(m0 + row) * DM + k0 + scol),
              ld_bf8(Bt + (size_t)(n0 + row) * DM + k0 + scol), DM)
    // C/D: col = lane&15, row = quad*4 + reg (m89-verified).
    for (int mt = 0; mt < 4; ++mt)
        for (int nt = 0; nt < 4; ++nt) {
            int cc = n0 + wn * 64 + nt * 16 + col;       // [0,3072)
            int which = cc >> 10;                        // 0=Q 1=K 2=V
            int c1 = cc & 1023;
            int h = c1 >> 6, d = c1 & 63;
            for (int r = 0; r < 4; ++r) {
                int row = m0 + wm * 64 + mt * 16 + quad * 4 + r;   // [0,4096)
                int b = row >> 11, s = row & (SEQ - 1);
                u16 val = f2b(acc[mt][nt][r]);
                size_t bh = (size_t)(b * HEADS + h);
                if (which == 0)
                    Qp[(bh * SEQ + s) * 64 + d] = val;
                else if (which == 1)
                    Kp[(bh * SEQ + s) * 64 + d] = val;
                else
                    Vt[(bh * 64 + d) * SEQ + s] = val;
            }
        }
}

// ---------------------------------------------------------------------------
// Output GEMM: ao(4096x1024 bf16) x WoT(1024x1024 bf16)^T -> out FP32.
// ---------------------------------------------------------------------------
__global__ __launch_bounds__(256) void gemm_wo(const u16* __restrict__ A,
                                               const u16* __restrict__ Bt,
                                               float* __restrict__ C) {
    GEMM_BODY(ld_bf8(A + (size_t)(m0 + row) * DM + k0 + scol),
              ld_bf8(Bt + (size_t)(n0 + row) * DM + k0 + scol), DM)
    for (int mt = 0; mt < 4; ++mt)
        for (int nt = 0; nt < 4; ++nt)
            for (int r = 0; r < 4; ++r) {
                int row = m0 + wm * 64 + mt * 16 + quad * 4 + r;
                int cc  = n0 + wn * 64 + nt * 16 + col;
                C[(size_t)row * DM + cc] = acc[mt][nt][r];
            }
}

// ---------------------------------------------------------------------------
// RoPE for Q,K in-place on (bh,s,d) bf16; cos/sin fp32 (S x 32).
// token_positions == arange(SEQ). 8192 blocks x 256.
// ---------------------------------------------------------------------------
__global__ __launch_bounds__(256) void rope_qk(u16* __restrict__ Qp,
                                               u16* __restrict__ Kp,
                                               const float* __restrict__ cosT,
                                               const float* __restrict__ sinT) {
    int t = blockIdx.x * 256 + threadIdx.x;         // [0, 2^21)
    int p  = t & 31;
    int s  = (t >> 5) & (SEQ - 1);
    int hh = (t >> 16) & (HEADS - 1);
    int b  = t >> 20;

    float cv = cosT[s * 32 + p];
    float sv = sinT[s * 32 + p];

    size_t addr = (((size_t)(b * HEADS + hh)) * SEQ + s) * 64 + 2 * p;
    u32 q2 = *(const u32*)(Qp + addr);
    u32 k2 = *(const u32*)(Kp + addr);
    u32 qe_b = (q2 & 0xffff) << 16, qo_b = q2 & 0xffff0000u;
    u32 ke_b = (k2 & 0xffff) << 16, ko_b = k2 & 0xffff0000u;
    float qe, qo, ke, ko;
    __builtin_memcpy(&qe, &qe_b, 4); __builtin_memcpy(&qo, &qo_b, 4);
    __builtin_memcpy(&ke, &ke_b, 4); __builtin_memcpy(&ko, &ko_b, 4);

    u32 qout = (u32)f2b(cv * qe - sv * qo) | ((u32)f2b(sv * qe + cv * qo) << 16);
    u32 kout = (u32)f2b(cv * ke - sv * ko) | ((u32)f2b(sv * ke + cv * ko) << 16);
    *(u32*)(Qp + addr) = qout;
    *(u32*)(Kp + addr) = kout;
}

// ---------------------------------------------------------------------------
// Causal flash attention. One wave per 16-query tile; 32-key tiles.
// Qp,Kp: (bh, s, 64)  Vt: (bh, 64, s)  O: (b, s, h*64+d)  bf16
// ---------------------------------------------------------------------------
__global__ __launch_bounds__(256) void flash_attn(const u16* __restrict__ Qp,
                                                  const u16* __restrict__ Kp,
                                                  const u16* __restrict__ Vt,
                                                  u16* __restrict__ O) {
    __shared__ __bf16 Plds[4][16][32];     // per-wave P tile
    const int tid  = threadIdx.x;
    const int wave = tid >> 6, lane = tid & 63;
    const int quad = lane >> 4, col = lane & 15;
    const int bh = blockIdx.y;
    const int b = bh >> 4, h = bh & 15;
    const int q0 = (31 - blockIdx.x) * 64 + wave * 16;   // heavy blocks first

    const u16* Qb = Qp + (size_t)bh * SEQ * 64;
    const u16* Kb = Kp + (size_t)bh * SEQ * 64;
    const u16* Vb = Vt + (size_t)bh * 64 * SEQ;

    // Q A-fragments (m=lane&15, k=quad*8+j), two K-steps for dk=64
    bf16x8 aq0 = *(const bf16x8*)(Qb + (size_t)(q0 + col) * 64 + quad * 8);
    bf16x8 aq1 = *(const bf16x8*)(Qb + (size_t)(q0 + col) * 64 + 32 + quad * 8);

    f32x4 zero = {0.f, 0.f, 0.f, 0.f};
    f32x4 o[4];
    float m_i[4], l_i[4];
    for (int r = 0; r < 4; ++r) { m_i[r] = -1e30f; l_i[r] = 0.f; o[r] = zero; }

    const int ntiles = (q0 + 47) >> 5;   // ceil((q0+16)/32); kb_last <= q0
    for (int kt = 0; kt < ntiles; ++kt) {
        const int kb = kt << 5;
        // ---- S = Q K^T * scale, two 16-key column tiles
        bf16x8 b00 = *(const bf16x8*)(Kb + (size_t)(kb + col) * 64 + quad * 8);
        bf16x8 b01 = *(const bf16x8*)(Kb + (size_t)(kb + col) * 64 + 32 + quad * 8);
        bf16x8 b10 = *(const bf16x8*)(Kb + (size_t)(kb + 16 + col) * 64 + quad * 8);
        bf16x8 b11 = *(const bf16x8*)(Kb + (size_t)(kb + 16 + col) * 64 + 32 + quad * 8);
        f32x4 s0 = zero, s1 = zero;
        s0 = __builtin_amdgcn_mfma_f32_16x16x32_bf16(aq0, b00, s0, 0, 0, 0);
        s0 = __builtin_amdgcn_mfma_f32_16x16x32_bf16(aq1, b01, s0, 0, 0, 0);
        s1 = __builtin_amdgcn_mfma_f32_16x16x32_bf16(aq0, b10, s1, 0, 0, 0);
        s1 = __builtin_amdgcn_mfma_f32_16x16x32_bf16(aq1, b11, s1, 0, 0, 0);

        // ---- mask + online softmax (rows = quad*4+r, cols = lane&15)
        float p0[4], p1[4], mt4[4];
        for (int r = 0; r < 4; ++r) {
            int qrow = q0 + quad * 4 + r;
            float v0 = s0[r] * 0.125f;
            float v1 = s1[r] * 0.125f;
            if (kb + col > qrow)      v0 = -1e30f;
            if (kb + 16 + col > qrow) v1 = -1e30f;
            p0[r] = v0; p1[r] = v1;
            mt4[r] = fmaxf(v0, v1);
        }
        for (int d = 1; d < 16; d <<= 1)
            for (int r = 0; r < 4; ++r)
                mt4[r] = fmaxf(mt4[r], __shfl_xor(mt4[r], d));

        float rs[4];
        for (int r = 0; r < 4; ++r) {
            float mnew  = fmaxf(m_i[r], mt4[r]);
            float alpha = __expf(m_i[r] - mnew);
            m_i[r] = mnew;
            p0[r] = __expf(p0[r] - mnew);
            p1[r] = __expf(p1[r] - mnew);
            rs[r] = p0[r] + p1[r];
            l_i[r] *= alpha;
            for (int nt = 0; nt < 4; ++nt) o[nt][r] *= alpha;
        }
        for (int d = 1; d < 16; d <<= 1)
            for (int r = 0; r < 4; ++r)
                rs[r] += __shfl_xor(rs[r], d);
        for (int r = 0; r < 4; ++r) l_i[r] += rs[r];

        // ---- P (C-layout) -> LDS -> A-layout (wave-private, same-typed)
        for (int r = 0; r < 4; ++r) {
            Plds[wave][quad * 4 + r][col]      = (__bf16)p0[r];
            Plds[wave][quad * 4 + r][16 + col] = (__bf16)p1[r];
        }
        bf16x8 pf;
        for (int j = 0; j < 8; ++j)
            pf[j] = Plds[wave][col][quad * 8 + j];

        // ---- O += P V  (B-frag from Vt: contiguous 16B per lane)
        for (int nt = 0; nt < 4; ++nt) {
            bf16x8 bv = *(const bf16x8*)(Vb + (size_t)(nt * 16 + col) * SEQ + kb + quad * 8);
            o[nt] = __builtin_amdgcn_mfma_f32_16x16x32_bf16(pf, bv, o[nt], 0, 0, 0);
        }
    }

    for (int r = 0; r < 4; ++r) {
        float inv = 1.f / l_i[r];
        int qrow = q0 + quad * 4 + r;
        for (int nt = 0; nt < 4; ++nt)
            O[((size_t)b * SEQ + qrow) * DM + h * 64 + nt * 16 + col] = f2b(o[nt][r] * inv);
    }
}

// ---------------------------------------------------------------------------
extern "C" void kernel_launch(void* const* d_in, const int* in_sizes, int n_in,
                              void* d_out, int out_size, void* d_ws, size_t ws_size,
                              hipStream_t stream) {
    const float* x    = (const float*)d_in[0];   // fp32 inputs (R3->R5 proven)
    const float* Wq   = (const float*)d_in[2];
    const float* Wk   = (const float*)d_in[3];
    const float* Wv   = (const float*)d_in[4];
    const float* Wo   = (const float*)d_in[5];
    const float* cosT = (const float*)d_in[6];
    const float* sinT = (const float*)d_in[7];
    float* out = (float*)d_out;                  // fp32 output (R8 proven)

    // Workspace: 16,777,216 u16 = 32 MiB (R8-proven safe size).
    u16* ws    = (u16*)d_ws;
    u16* qp    = ws;               // (bh,s,d)
    u16* kp    = ws + 4194304;
    u16* vt    = ws + 8388608;     // (bh,d,s); dead after flash
    u16* woT   = ws + 8388608;     // overlays vt, written after flash
    u16* wqkvT = ws + 12582912;    // dead after gemm_qkv
    u16* ao    = ws + 12582912;    // overlays wqkvT

    dim3 blk(256);
    transpose_wqkv<<<dim3(16, 16, 3), blk, 0, stream>>>(Wq, Wk, Wv, wqkvT);
    gemm_qkv<<<dim3(32, 24), blk, 0, stream>>>(x, wqkvT, qp, kp, vt);
    rope_qk<<<dim3(8192), blk, 0, stream>>>(qp, kp, cosT, sinT);
    flash_attn<<<dim3(32, NBH), blk, 0, stream>>>(qp, kp, vt, ao);
    transpose_wo<<<dim3(16, 16), blk, 0, stream>>>(Wo, woT);
    gemm_wo<<<dim3(32, 8), blk, 0, stream>>>(ao, woT, out);
}

// Round 10
// 300.112 us; speedup vs baseline: 23.5928x; 1.3431x over previous
//
#include <hip/hip_runtime.h>

typedef unsigned short u16;
typedef unsigned int   u32;
typedef __bf16  bf16x8 __attribute__((ext_vector_type(8)));
typedef float   f32x4  __attribute__((ext_vector_type(4)));

#define SEQ    2048
#define HEADS  16
#define DM     1024
#define NBH    32      /* B*H */
#define NBS    4096    /* B*S */

__device__ __forceinline__ u16 f2b(float f) {
    u32 x;
    __builtin_memcpy(&x, &f, 4);
    return (u16)((x + 0x7fffu + ((x >> 16) & 1u)) >> 16);  // RNE
}

__device__ __forceinline__ bf16x8 ld_bf8(const u16* p) {
    return *(const bf16x8*)p;
}
__device__ __forceinline__ bf16x8 ld_f32x8_cvt(const float* p) {
    f32x4 a = *(const f32x4*)p;
    f32x4 b = *(const f32x4*)(p + 4);
    bf16x8 r;
    r[0] = (__bf16)a[0]; r[1] = (__bf16)a[1]; r[2] = (__bf16)a[2]; r[3] = (__bf16)a[3];
    r[4] = (__bf16)b[0]; r[5] = (__bf16)b[1]; r[6] = (__bf16)b[2]; r[7] = (__bf16)b[3];
    return r;
}

// ---------------------------------------------------------------------------
// Transpose + fp32->bf16 of W_Q/W_K/W_V: (k,n) -> WqkvT[z*1024 + n][k].
// ---------------------------------------------------------------------------
__global__ __launch_bounds__(256) void transpose_wqkv(const float* __restrict__ Wq,
                                                      const float* __restrict__ Wk,
                                                      const float* __restrict__ Wv,
                                                      u16* __restrict__ WqkvT) {
    __shared__ u16 tile[64][65];
    const int z  = blockIdx.z;
    const float* src = (z == 0) ? Wq : (z == 1) ? Wk : Wv;
    const int k0 = blockIdx.x * 64, n0 = blockIdx.y * 64;
    const int tid = threadIdx.x;
    for (int i = 0; i < 16; ++i) {
        int e = i * 256 + tid;
        int r = e >> 6, c = e & 63;
        tile[r][c] = f2b(src[(size_t)(k0 + r) * DM + n0 + c]);
    }
    __syncthreads();
    u16* dst = WqkvT + (size_t)z * DM * DM;
    for (int i = 0; i < 16; ++i) {
        int e = i * 256 + tid;
        int r = e >> 6, c = e & 63;
        dst[(size_t)(n0 + r) * DM + k0 + c] = tile[c][r];
    }
}

// W_O (k,n) fp32 -> WoT[n][k] bf16. Launched AFTER flash (overlays dead vt).
__global__ __launch_bounds__(256) void transpose_wo(const float* __restrict__ Wo,
                                                    u16* __restrict__ WoT) {
    __shared__ u16 tile[64][65];
    const int k0 = blockIdx.x * 64, n0 = blockIdx.y * 64;
    const int tid = threadIdx.x;
    for (int i = 0; i < 16; ++i) {
        int e = i * 256 + tid;
        int r = e >> 6, c = e & 63;
        tile[r][c] = f2b(Wo[(size_t)(k0 + r) * DM + n0 + c]);
    }
    __syncthreads();
    for (int i = 0; i < 16; ++i) {
        int e = i * 256 + tid;
        int r = e >> 6, c = e & 63;
        WoT[(size_t)(n0 + r) * DM + k0 + c] = tile[c][r];
    }
}

// ---------------------------------------------------------------------------
// Shared GEMM body: 128x128 tile, BK=64, VGPR-mediated staging,
// 4 waves 2x2, 4x4 16x16x32 MFMA tiles per wave. acc[][] left for epilogue.
// ---------------------------------------------------------------------------
#define GEMM_BODY(A_EXPR, B_EXPR, K)                                                \
    __shared__ __attribute__((aligned(16))) __bf16 As[128 * 64];                    \
    __shared__ __attribute__((aligned(16))) __bf16 Bs[128 * 64];                    \
    const int tid  = threadIdx.x;                                                   \
    const int wave = tid >> 6, lane = tid & 63;                                     \
    const int quad = lane >> 4, col = lane & 15;                                    \
    const int wm = wave >> 1, wn = wave & 1;                                        \
    const int m0 = blockIdx.x * 128, n0 = blockIdx.y * 128;                         \
    const int srow = tid >> 3;            /* 0..31 */                               \
    const int scol = (tid & 7) * 8;       /* 0..56 */                               \
    f32x4 zero = {0.f, 0.f, 0.f, 0.f};                                              \
    f32x4 acc[4][4];                                                                \
    for (int i = 0; i < 4; ++i)                                                     \
        for (int j = 0; j < 4; ++j) acc[i][j] = zero;                               \
    for (int k0 = 0; k0 < (K); k0 += 64) {                                          \
        bf16x8 av[4], bv[4];                                                        \
        for (int p = 0; p < 4; ++p) {                                               \
            int row = p * 32 + srow;                                                \
            av[p] = A_EXPR;                                                         \
            bv[p] = B_EXPR;                                                         \
        }                                                                           \
        __syncthreads();                                                            \
        for (int p = 0; p < 4; ++p) {                                               \
            int row = p * 32 + srow;                                                \
            *(bf16x8*)&As[row * 64 + scol] = av[p];                                 \
            *(bf16x8*)&Bs[row * 64 + scol] = bv[p];                                 \
        }                                                                           \
        __syncthreads();                                                            \
        for (int ks = 0; ks < 2; ++ks) {                                            \
            bf16x8 af[4], bfr[4];                                                   \
            for (int mt = 0; mt < 4; ++mt)                                          \
                af[mt] = *(const bf16x8*)&As[(wm * 64 + mt * 16 + col) * 64 +       \
                                             ks * 32 + quad * 8];                   \
            for (int nt = 0; nt < 4; ++nt)                                          \
                bfr[nt] = *(const bf16x8*)&Bs[(wn * 64 + nt * 16 + col) * 64 +      \
                                              ks * 32 + quad * 8];                  \
            for (int mt = 0; mt < 4; ++mt)                                          \
                for (int nt = 0; nt < 4; ++nt)                                      \
                    acc[mt][nt] = __builtin_amdgcn_mfma_f32_16x16x32_bf16(          \
                        af[mt], bfr[nt], acc[mt][nt], 0, 0, 0);                     \
        }                                                                           \
    }

// ---------------------------------------------------------------------------
// Fused QKV GEMM: x(4096x1024 fp32) x WqkvT(3072x1024 bf16)^T.
// Epilogue scatters to Qp (bh,s,d), Kp (bh,s,d), Vt (bh,d,s).
// ---------------------------------------------------------------------------
__global__ __launch_bounds__(256) void gemm_qkv(const float* __restrict__ Af,
                                                const u16* __restrict__ Bt,
                                                u16* __restrict__ Qp,
                                                u16* __restrict__ Kp,
                                                u16* __restrict__ Vt) {
    GEMM_BODY(ld_f32x8_cvt(Af + (size_t)(m0 + row) * DM + k0 + scol),
              ld_bf8(Bt + (size_t)(n0 + row) * DM + k0 + scol), DM)
    // C/D: col = lane&15, row = quad*4 + reg (m89-verified).
    for (int mt = 0; mt < 4; ++mt)
        for (int nt = 0; nt < 4; ++nt) {
            int cc = n0 + wn * 64 + nt * 16 + col;       // [0,3072)
            int which = cc >> 10;                        // 0=Q 1=K 2=V
            int c1 = cc & 1023;
            int h = c1 >> 6, d = c1 & 63;
            for (int r = 0; r < 4; ++r) {
                int row = m0 + wm * 64 + mt * 16 + quad * 4 + r;   // [0,4096)
                int b = row >> 11, s = row & (SEQ - 1);
                u16 val = f2b(acc[mt][nt][r]);
                size_t bh = (size_t)(b * HEADS + h);
                if (which == 0)
                    Qp[(bh * SEQ + s) * 64 + d] = val;
                else if (which == 1)
                    Kp[(bh * SEQ + s) * 64 + d] = val;
                else
                    Vt[(bh * 64 + d) * SEQ + s] = val;
            }
        }
}

// ---------------------------------------------------------------------------
// Output GEMM: ao(4096x1024 bf16) x WoT(1024x1024 bf16)^T -> out FP32.
// ---------------------------------------------------------------------------
__global__ __launch_bounds__(256) void gemm_wo(const u16* __restrict__ A,
                                               const u16* __restrict__ Bt,
                                               float* __restrict__ C) {
    GEMM_BODY(ld_bf8(A + (size_t)(m0 + row) * DM + k0 + scol),
              ld_bf8(Bt + (size_t)(n0 + row) * DM + k0 + scol), DM)
    for (int mt = 0; mt < 4; ++mt)
        for (int nt = 0; nt < 4; ++nt)
            for (int r = 0; r < 4; ++r) {
                int row = m0 + wm * 64 + mt * 16 + quad * 4 + r;
                int cc  = n0 + wn * 64 + nt * 16 + col;
                C[(size_t)row * DM + cc] = acc[mt][nt][r];
            }
}

// ---------------------------------------------------------------------------
// RoPE for Q,K in-place on (bh,s,d) bf16; cos/sin fp32 (S x 32).
// token_positions == arange(SEQ). 8192 blocks x 256.
// ---------------------------------------------------------------------------
__global__ __launch_bounds__(256) void rope_qk(u16* __restrict__ Qp,
                                               u16* __restrict__ Kp,
                                               const float* __restrict__ cosT,
                                               const float* __restrict__ sinT) {
    int t = blockIdx.x * 256 + threadIdx.x;         // [0, 2^21)
    int p  = t & 31;
    int s  = (t >> 5) & (SEQ - 1);
    int hh = (t >> 16) & (HEADS - 1);
    int b  = t >> 20;

    float cv = cosT[s * 32 + p];
    float sv = sinT[s * 32 + p];

    size_t addr = (((size_t)(b * HEADS + hh)) * SEQ + s) * 64 + 2 * p;
    u32 q2 = *(const u32*)(Qp + addr);
    u32 k2 = *(const u32*)(Kp + addr);
    u32 qe_b = (q2 & 0xffff) << 16, qo_b = q2 & 0xffff0000u;
    u32 ke_b = (k2 & 0xffff) << 16, ko_b = k2 & 0xffff0000u;
    float qe, qo, ke, ko;
    __builtin_memcpy(&qe, &qe_b, 4); __builtin_memcpy(&qo, &qo_b, 4);
    __builtin_memcpy(&ke, &ke_b, 4); __builtin_memcpy(&ko, &ko_b, 4);

    u32 qout = (u32)f2b(cv * qe - sv * qo) | ((u32)f2b(sv * qe + cv * qo) << 16);
    u32 kout = (u32)f2b(cv * ke - sv * ko) | ((u32)f2b(sv * ke + cv * ko) << 16);
    *(u32*)(Qp + addr) = qout;
    *(u32*)(Kp + addr) = kout;
}

// ---------------------------------------------------------------------------
// Causal flash attention, PAIRED query tiles for load balance + K/V reuse.
// Block = (i, bh), i in [0,16): handles 64-query tiles i and 31-i.
// Each wave: 16 queries of tile i (half 0, light) + 16 of tile 31-i (half 1,
// heavy). Work per wave = (i+1)+(32-i) ~ const -> no tail. K/V fragments are
// shared by both halves (2x MFMA per load, 2 independent chains for ILP).
// Qp,Kp: (bh, s, 64)  Vt: (bh, 64, s)  O: (b, s, h*64+d)  bf16
// ---------------------------------------------------------------------------
__global__ __launch_bounds__(256) void flash_attn(const u16* __restrict__ Qp,
                                                  const u16* __restrict__ Kp,
                                                  const u16* __restrict__ Vt,
                                                  u16* __restrict__ O) {
    __shared__ __bf16 Plds[4][2][16][32];   // [wave][half][row][key]
    const int tid  = threadIdx.x;
    const int wave = tid >> 6, lane = tid & 63;
    const int quad = lane >> 4, col = lane & 15;
    const int bh = blockIdx.y;
    const int b = bh >> 4, h = bh & 15;
    const int i = blockIdx.x;                              // [0,16)
    const int q0h[2] = { i * 64 + wave * 16,
                         (31 - i) * 64 + wave * 16 };

    const u16* Qb = Qp + (size_t)bh * SEQ * 64;
    const u16* Kb = Kp + (size_t)bh * SEQ * 64;
    const u16* Vb = Vt + (size_t)bh * 64 * SEQ;

    // Q A-fragments (m=lane&15, k=quad*8+j), two K-steps for dk=64
    bf16x8 aq[2][2];
    for (int hf = 0; hf < 2; ++hf) {
        aq[hf][0] = ld_bf8(Qb + (size_t)(q0h[hf] + col) * 64 + quad * 8);
        aq[hf][1] = ld_bf8(Qb + (size_t)(q0h[hf] + col) * 64 + 32 + quad * 8);
    }

    f32x4 zero = {0.f, 0.f, 0.f, 0.f};
    f32x4 o[2][4];
    float m_i[2][4], l_i[2][4];
    for (int hf = 0; hf < 2; ++hf)
        for (int r = 0; r < 4; ++r) {
            m_i[hf][r] = -1e30f; l_i[hf][r] = 0.f; o[hf][r] = zero;
        }

    const int nth[2] = { (q0h[0] + 47) >> 5, (q0h[1] + 47) >> 5 };
    for (int kt = 0; kt < nth[1]; ++kt) {
        const int kb = kt << 5;
        // ---- K fragments for 32 keys (shared by both halves)
        bf16x8 kf00 = ld_bf8(Kb + (size_t)(kb + col) * 64 + quad * 8);
        bf16x8 kf01 = ld_bf8(Kb + (size_t)(kb + col) * 64 + 32 + quad * 8);
        bf16x8 kf10 = ld_bf8(Kb + (size_t)(kb + 16 + col) * 64 + quad * 8);
        bf16x8 kf11 = ld_bf8(Kb + (size_t)(kb + 16 + col) * 64 + 32 + quad * 8);

        for (int hf = 0; hf < 2; ++hf) {
            if (kt >= nth[hf]) continue;          // light half done (wave-uniform)
            f32x4 s0 = zero, s1 = zero;
            s0 = __builtin_amdgcn_mfma_f32_16x16x32_bf16(aq[hf][0], kf00, s0, 0, 0, 0);
            s0 = __builtin_amdgcn_mfma_f32_16x16x32_bf16(aq[hf][1], kf01, s0, 0, 0, 0);
            s1 = __builtin_amdgcn_mfma_f32_16x16x32_bf16(aq[hf][0], kf10, s1, 0, 0, 0);
            s1 = __builtin_amdgcn_mfma_f32_16x16x32_bf16(aq[hf][1], kf11, s1, 0, 0, 0);

            // mask + online softmax (rows = quad*4+r, cols = lane&15)
            float p0[4], p1[4], mt4[4];
            for (int r = 0; r < 4; ++r) {
                int qrow = q0h[hf] + quad * 4 + r;
                float v0 = s0[r] * 0.125f;
                float v1 = s1[r] * 0.125f;
                if (kb + col > qrow)      v0 = -1e30f;
                if (kb + 16 + col > qrow) v1 = -1e30f;
                p0[r] = v0; p1[r] = v1;
                mt4[r] = fmaxf(v0, v1);
            }
            for (int d = 1; d < 16; d <<= 1)
                for (int r = 0; r < 4; ++r)
                    mt4[r] = fmaxf(mt4[r], __shfl_xor(mt4[r], d));

            float rs[4];
            for (int r = 0; r < 4; ++r) {
                float mnew  = fmaxf(m_i[hf][r], mt4[r]);
                float alpha = __expf(m_i[hf][r] - mnew);
                m_i[hf][r] = mnew;
                p0[r] = __expf(p0[r] - mnew);
                p1[r] = __expf(p1[r] - mnew);
                rs[r] = p0[r] + p1[r];
                l_i[hf][r] *= alpha;
                for (int nt = 0; nt < 4; ++nt) o[hf][nt][r] *= alpha;
            }
            for (int d = 1; d < 16; d <<= 1)
                for (int r = 0; r < 4; ++r)
                    rs[r] += __shfl_xor(rs[r], d);
            for (int r = 0; r < 4; ++r) l_i[hf][r] += rs[r];

            // P (C-layout) -> LDS (wave-private half-slot)
            for (int r = 0; r < 4; ++r) {
                Plds[wave][hf][quad * 4 + r][col]      = (__bf16)p0[r];
                Plds[wave][hf][quad * 4 + r][16 + col] = (__bf16)p1[r];
            }
        }

        // ---- P A-fragments for both halves, then PV (V shared)
        bf16x8 pf[2];
        for (int hf = 0; hf < 2; ++hf) {
            if (kt >= nth[hf]) continue;
            for (int j = 0; j < 8; ++j)
                pf[hf][j] = Plds[wave][hf][col][quad * 8 + j];
        }
        for (int nt = 0; nt < 4; ++nt) {
            bf16x8 bv = ld_bf8(Vb + (size_t)(nt * 16 + col) * SEQ + kb + quad * 8);
            if (kt < nth[0])
                o[0][nt] = __builtin_amdgcn_mfma_f32_16x16x32_bf16(pf[0], bv, o[0][nt], 0, 0, 0);
            o[1][nt] = __builtin_amdgcn_mfma_f32_16x16x32_bf16(pf[1], bv, o[1][nt], 0, 0, 0);
        }
    }

    for (int hf = 0; hf < 2; ++hf)
        for (int r = 0; r < 4; ++r) {
            float inv = 1.f / l_i[hf][r];
            int qrow = q0h[hf] + quad * 4 + r;
            for (int nt = 0; nt < 4; ++nt)
                O[((size_t)b * SEQ + qrow) * DM + h * 64 + nt * 16 + col] =
                    f2b(o[hf][nt][r] * inv);
        }
}

// ---------------------------------------------------------------------------
extern "C" void kernel_launch(void* const* d_in, const int* in_sizes, int n_in,
                              void* d_out, int out_size, void* d_ws, size_t ws_size,
                              hipStream_t stream) {
    const float* x    = (const float*)d_in[0];   // fp32 inputs (R3->R5 proven)
    const float* Wq   = (const float*)d_in[2];
    const float* Wk   = (const float*)d_in[3];
    const float* Wv   = (const float*)d_in[4];
    const float* Wo   = (const float*)d_in[5];
    const float* cosT = (const float*)d_in[6];
    const float* sinT = (const float*)d_in[7];
    float* out = (float*)d_out;                  // fp32 output (R8 proven)

    // Workspace: 16,777,216 u16 = 32 MiB (R8-proven safe size).
    u16* ws    = (u16*)d_ws;
    u16* qp    = ws;               // (bh,s,d)
    u16* kp    = ws + 4194304;
    u16* vt    = ws + 8388608;     // (bh,d,s); dead after flash
    u16* woT   = ws + 8388608;     // overlays vt, written after flash
    u16* wqkvT = ws + 12582912;    // dead after gemm_qkv
    u16* ao    = ws + 12582912;    // overlays wqkvT

    dim3 blk(256);
    transpose_wqkv<<<dim3(16, 16, 3), blk, 0, stream>>>(Wq, Wk, Wv, wqkvT);
    gemm_qkv<<<dim3(32, 24), blk, 0, stream>>>(x, wqkvT, qp, kp, vt);
    rope_qk<<<dim3(8192), blk, 0, stream>>>(qp, kp, cosT, sinT);
    flash_attn<<<dim3(16, NBH), blk, 0, stream>>>(qp, kp, vt, ao);
    transpose_wo<<<dim3(16, 16), blk, 0, stream>>>(Wo, woT);
    gemm_wo<<<dim3(32, 8), blk, 0, stream>>>(ao, woT, out);
}

// Round 11
// 293.965 us; speedup vs baseline: 24.0862x; 1.0209x over previous
//
#include <hip/hip_runtime.h>

typedef unsigned short u16;
typedef unsigned int   u32;
typedef __bf16  bf16x8 __attribute__((ext_vector_type(8)));
typedef float   f32x4  __attribute__((ext_vector_type(4)));

#define SEQ    2048
#define HEADS  16
#define DM     1024
#define NBH    32      /* B*H */
#define NBS    4096    /* B*S */

__device__ __forceinline__ u16 f2b(float f) {
    u32 x;
    __builtin_memcpy(&x, &f, 4);
    return (u16)((x + 0x7fffu + ((x >> 16) & 1u)) >> 16);  // RNE
}

__device__ __forceinline__ bf16x8 ld_bf8(const u16* p) {
    return *(const bf16x8*)p;
}
__device__ __forceinline__ bf16x8 ld_f32x8_cvt(const float* p) {
    f32x4 a = *(const f32x4*)p;
    f32x4 b = *(const f32x4*)(p + 4);
    bf16x8 r;
    r[0] = (__bf16)a[0]; r[1] = (__bf16)a[1]; r[2] = (__bf16)a[2]; r[3] = (__bf16)a[3];
    r[4] = (__bf16)b[0]; r[5] = (__bf16)b[1]; r[6] = (__bf16)b[2]; r[7] = (__bf16)b[3];
    return r;
}

// ---------------------------------------------------------------------------
// Transpose + fp32->bf16 of W_Q/W_K/W_V: (k,n) -> WqkvT[z*1024 + n][k].
// ---------------------------------------------------------------------------
__global__ __launch_bounds__(256) void transpose_wqkv(const float* __restrict__ Wq,
                                                      const float* __restrict__ Wk,
                                                      const float* __restrict__ Wv,
                                                      u16* __restrict__ WqkvT) {
    __shared__ u16 tile[64][65];
    const int z  = blockIdx.z;
    const float* src = (z == 0) ? Wq : (z == 1) ? Wk : Wv;
    const int k0 = blockIdx.x * 64, n0 = blockIdx.y * 64;
    const int tid = threadIdx.x;
    for (int i = 0; i < 16; ++i) {
        int e = i * 256 + tid;
        int r = e >> 6, c = e & 63;
        tile[r][c] = f2b(src[(size_t)(k0 + r) * DM + n0 + c]);
    }
    __syncthreads();
    u16* dst = WqkvT + (size_t)z * DM * DM;
    for (int i = 0; i < 16; ++i) {
        int e = i * 256 + tid;
        int r = e >> 6, c = e & 63;
        dst[(size_t)(n0 + r) * DM + k0 + c] = tile[c][r];
    }
}

// W_O (k,n) fp32 -> WoT[n][k] bf16. Launched AFTER flash (overlays dead vt).
__global__ __launch_bounds__(256) void transpose_wo(const float* __restrict__ Wo,
                                                    u16* __restrict__ WoT) {
    __shared__ u16 tile[64][65];
    const int k0 = blockIdx.x * 64, n0 = blockIdx.y * 64;
    const int tid = threadIdx.x;
    for (int i = 0; i < 16; ++i) {
        int e = i * 256 + tid;
        int r = e >> 6, c = e & 63;
        tile[r][c] = f2b(Wo[(size_t)(k0 + r) * DM + n0 + c]);
    }
    __syncthreads();
    for (int i = 0; i < 16; ++i) {
        int e = i * 256 + tid;
        int r = e >> 6, c = e & 63;
        WoT[(size_t)(n0 + r) * DM + k0 + c] = tile[c][r];
    }
}

// ---------------------------------------------------------------------------
// Shared GEMM body: 128x128 tile, BK=64, VGPR-mediated staging,
// 4 waves 2x2, 4x4 16x16x32 MFMA tiles per wave. acc[][] left for epilogue.
// ---------------------------------------------------------------------------
#define GEMM_BODY(A_EXPR, B_EXPR, K)                                                \
    __shared__ __attribute__((aligned(16))) __bf16 As[128 * 64];                    \
    __shared__ __attribute__((aligned(16))) __bf16 Bs[128 * 64];                    \
    const int tid  = threadIdx.x;                                                   \
    const int wave = tid >> 6, lane = tid & 63;                                     \
    const int quad = lane >> 4, col = lane & 15;                                    \
    const int wm = wave >> 1, wn = wave & 1;                                        \
    const int m0 = blockIdx.x * 128, n0 = blockIdx.y * 128;                         \
    const int srow = tid >> 3;            /* 0..31 */                               \
    const int scol = (tid & 7) * 8;       /* 0..56 */                               \
    f32x4 zero = {0.f, 0.f, 0.f, 0.f};                                              \
    f32x4 acc[4][4];                                                                \
    for (int i = 0; i < 4; ++i)                                                     \
        for (int j = 0; j < 4; ++j) acc[i][j] = zero;                               \
    for (int k0 = 0; k0 < (K); k0 += 64) {                                          \
        bf16x8 av[4], bv[4];                                                        \
        for (int p = 0; p < 4; ++p) {                                               \
            int row = p * 32 + srow;                                                \
            av[p] = A_EXPR;                                                         \
            bv[p] = B_EXPR;                                                         \
        }                                                                           \
        __syncthreads();                                                            \
        for (int p = 0; p < 4; ++p) {                                               \
            int row = p * 32 + srow;                                                \
            *(bf16x8*)&As[row * 64 + scol] = av[p];                                 \
            *(bf16x8*)&Bs[row * 64 + scol] = bv[p];                                 \
        }                                                                           \
        __syncthreads();                                                            \
        for (int ks = 0; ks < 2; ++ks) {                                            \
            bf16x8 af[4], bfr[4];                                                   \
            for (int mt = 0; mt < 4; ++mt)                                          \
                af[mt] = *(const bf16x8*)&As[(wm * 64 + mt * 16 + col) * 64 +       \
                                             ks * 32 + quad * 8];                   \
            for (int nt = 0; nt < 4; ++nt)                                          \
                bfr[nt] = *(const bf16x8*)&Bs[(wn * 64 + nt * 16 + col) * 64 +      \
                                              ks * 32 + quad * 8];                  \
            for (int mt = 0; mt < 4; ++mt)                                          \
                for (int nt = 0; nt < 4; ++nt)                                      \
                    acc[mt][nt] = __builtin_amdgcn_mfma_f32_16x16x32_bf16(          \
                        af[mt], bfr[nt], acc[mt][nt], 0, 0, 0);                     \
        }                                                                           \
    }

// ---------------------------------------------------------------------------
// Fused QKV GEMM: x(4096x1024 fp32) x WqkvT(3072x1024 bf16)^T.
// Epilogue scatters to Qp (bh,s,d), Kp (bh,s,d), Vt (bh,d,s).
// ---------------------------------------------------------------------------
__global__ __launch_bounds__(256) void gemm_qkv(const float* __restrict__ Af,
                                                const u16* __restrict__ Bt,
                                                u16* __restrict__ Qp,
                                                u16* __restrict__ Kp,
                                                u16* __restrict__ Vt) {
    GEMM_BODY(ld_f32x8_cvt(Af + (size_t)(m0 + row) * DM + k0 + scol),
              ld_bf8(Bt + (size_t)(n0 + row) * DM + k0 + scol), DM)
    // C/D: col = lane&15, row = quad*4 + reg (m89-verified).
    for (int mt = 0; mt < 4; ++mt)
        for (int nt = 0; nt < 4; ++nt) {
            int cc = n0 + wn * 64 + nt * 16 + col;       // [0,3072)
            int which = cc >> 10;                        // 0=Q 1=K 2=V
            int c1 = cc & 1023;
            int h = c1 >> 6, d = c1 & 63;
            for (int r = 0; r < 4; ++r) {
                int row = m0 + wm * 64 + mt * 16 + quad * 4 + r;   // [0,4096)
                int b = row >> 11, s = row & (SEQ - 1);
                u16 val = f2b(acc[mt][nt][r]);
                size_t bh = (size_t)(b * HEADS + h);
                if (which == 0)
                    Qp[(bh * SEQ + s) * 64 + d] = val;
                else if (which == 1)
                    Kp[(bh * SEQ + s) * 64 + d] = val;
                else
                    Vt[(bh * 64 + d) * SEQ + s] = val;
            }
        }
}

// ---------------------------------------------------------------------------
// Output GEMM: ao(4096x1024 bf16) x WoT(1024x1024 bf16)^T -> out FP32.
// ---------------------------------------------------------------------------
__global__ __launch_bounds__(256) void gemm_wo(const u16* __restrict__ A,
                                               const u16* __restrict__ Bt,
                                               float* __restrict__ C) {
    GEMM_BODY(ld_bf8(A + (size_t)(m0 + row) * DM + k0 + scol),
              ld_bf8(Bt + (size_t)(n0 + row) * DM + k0 + scol), DM)
    for (int mt = 0; mt < 4; ++mt)
        for (int nt = 0; nt < 4; ++nt)
            for (int r = 0; r < 4; ++r) {
                int row = m0 + wm * 64 + mt * 16 + quad * 4 + r;
                int cc  = n0 + wn * 64 + nt * 16 + col;
                C[(size_t)row * DM + cc] = acc[mt][nt][r];
            }
}

// ---------------------------------------------------------------------------
// RoPE for Q,K in-place on (bh,s,d) bf16; cos/sin fp32 (S x 32).
// token_positions == arange(SEQ). 8192 blocks x 256.
// ---------------------------------------------------------------------------
__global__ __launch_bounds__(256) void rope_qk(u16* __restrict__ Qp,
                                               u16* __restrict__ Kp,
                                               const float* __restrict__ cosT,
                                               const float* __restrict__ sinT) {
    int t = blockIdx.x * 256 + threadIdx.x;         // [0, 2^21)
    int p  = t & 31;
    int s  = (t >> 5) & (SEQ - 1);
    int hh = (t >> 16) & (HEADS - 1);
    int b  = t >> 20;

    float cv = cosT[s * 32 + p];
    float sv = sinT[s * 32 + p];

    size_t addr = (((size_t)(b * HEADS + hh)) * SEQ + s) * 64 + 2 * p;
    u32 q2 = *(const u32*)(Qp + addr);
    u32 k2 = *(const u32*)(Kp + addr);
    u32 qe_b = (q2 & 0xffff) << 16, qo_b = q2 & 0xffff0000u;
    u32 ke_b = (k2 & 0xffff) << 16, ko_b = k2 & 0xffff0000u;
    float qe, qo, ke, ko;
    __builtin_memcpy(&qe, &qe_b, 4); __builtin_memcpy(&qo, &qo_b, 4);
    __builtin_memcpy(&ke, &ke_b, 4); __builtin_memcpy(&ko, &ko_b, 4);

    u32 qout = (u32)f2b(cv * qe - sv * qo) | ((u32)f2b(sv * qe + cv * qo) << 16);
    u32 kout = (u32)f2b(cv * ke - sv * ko) | ((u32)f2b(sv * ke + cv * ko) << 16);
    *(u32*)(Qp + addr) = qout;
    *(u32*)(Kp + addr) = kout;
}

// ---------------------------------------------------------------------------
// Causal flash attention, paired query tiles + TRANSPOSED scores.
// S^T = K Q^T: C col = lane&15 -> query, row = quad*4+r -> key. Each lane
// owns all scores of ONE query -> softmax reductions are in-lane + 2 shfl
// (xor16, xor32 across quad copies) instead of 4-step x 4-row per half.
// Block = (i, bh), i in [0,16): tiles i (light) and 31-i (heavy).
// Qp,Kp: (bh, s, 64)  Vt: (bh, 64, s)  O: (b, s, h*64+d)  bf16
// ---------------------------------------------------------------------------
__global__ __launch_bounds__(256) void flash_attn(const u16* __restrict__ Qp,
                                                  const u16* __restrict__ Kp,
                                                  const u16* __restrict__ Vt,
                                                  u16* __restrict__ O) {
    __shared__ __bf16 Plds[4][2][16][32];   // [wave][half][query][key]
    const int tid  = threadIdx.x;
    const int wave = tid >> 6, lane = tid & 63;
    const int quad = lane >> 4, col = lane & 15;
    const int bh = blockIdx.y;
    const int b = bh >> 4, h = bh & 15;
    const int i = blockIdx.x;                              // [0,16)
    const int q0h[2] = { i * 64 + wave * 16,
                         (31 - i) * 64 + wave * 16 };

    const u16* Qb = Qp + (size_t)bh * SEQ * 64;
    const u16* Kb = Kp + (size_t)bh * SEQ * 64;
    const u16* Vb = Vt + (size_t)bh * 64 * SEQ;

    // Q as B-operand (n=lane&15 -> query, k=quad*8+j), two K-steps for dk=64
    bf16x8 bq[2][2];
    for (int hf = 0; hf < 2; ++hf) {
        bq[hf][0] = ld_bf8(Qb + (size_t)(q0h[hf] + col) * 64 + quad * 8);
        bq[hf][1] = ld_bf8(Qb + (size_t)(q0h[hf] + col) * 64 + 32 + quad * 8);
    }

    f32x4 zero = {0.f, 0.f, 0.f, 0.f};
    f32x4 o[2][4];
    float m_i[2], l_i[2];                    // per-lane state for query q0h+col
    for (int hf = 0; hf < 2; ++hf) {
        m_i[hf] = -1e30f; l_i[hf] = 0.f;
        for (int nt = 0; nt < 4; ++nt) o[hf][nt] = zero;
    }

    const int nth[2] = { (q0h[0] + 47) >> 5, (q0h[1] + 47) >> 5 };
    for (int kt = 0; kt < nth[1]; ++kt) {
        const int kb = kt << 5;
        // ---- K as A-operand (m=lane&15 -> key), shared by both halves
        bf16x8 ak00 = ld_bf8(Kb + (size_t)(kb + col) * 64 + quad * 8);
        bf16x8 ak01 = ld_bf8(Kb + (size_t)(kb + col) * 64 + 32 + quad * 8);
        bf16x8 ak10 = ld_bf8(Kb + (size_t)(kb + 16 + col) * 64 + quad * 8);
        bf16x8 ak11 = ld_bf8(Kb + (size_t)(kb + 16 + col) * 64 + 32 + quad * 8);

        for (int hf = 0; hf < 2; ++hf) {
            if (kt >= nth[hf]) continue;          // light half done (wave-uniform)
            // S^T tiles: st[t][r] = score(key = kb + t*16 + quad*4 + r, query)
            f32x4 st0 = zero, st1 = zero;
            st0 = __builtin_amdgcn_mfma_f32_16x16x32_bf16(ak00, bq[hf][0], st0, 0, 0, 0);
            st0 = __builtin_amdgcn_mfma_f32_16x16x32_bf16(ak01, bq[hf][1], st0, 0, 0, 0);
            st1 = __builtin_amdgcn_mfma_f32_16x16x32_bf16(ak10, bq[hf][0], st1, 0, 0, 0);
            st1 = __builtin_amdgcn_mfma_f32_16x16x32_bf16(ak11, bq[hf][1], st1, 0, 0, 0);

            const int qrow = q0h[hf] + col;
            float v0[4], v1[4];
            float lm = -1e30f;
            for (int r = 0; r < 4; ++r) {
                int key0 = kb + quad * 4 + r;
                int key1 = key0 + 16;
                float a = st0[r] * 0.125f;
                float c = st1[r] * 0.125f;
                if (key0 > qrow) a = -1e30f;
                if (key1 > qrow) c = -1e30f;
                v0[r] = a; v1[r] = c;
                lm = fmaxf(lm, fmaxf(a, c));
            }
            lm = fmaxf(lm, __shfl_xor(lm, 16));
            lm = fmaxf(lm, __shfl_xor(lm, 32));

            float mnew  = fmaxf(m_i[hf], lm);
            float alpha = __expf(m_i[hf] - mnew);
            m_i[hf] = mnew;
            float ls = 0.f;
            for (int r = 0; r < 4; ++r) {
                v0[r] = __expf(v0[r] - mnew);
                v1[r] = __expf(v1[r] - mnew);
                ls += v0[r] + v1[r];
            }
            ls += __shfl_xor(ls, 16);
            ls += __shfl_xor(ls, 32);
            l_i[hf] = l_i[hf] * alpha + ls;

            // rescale o (rows = query quad*4+r): broadcast alpha from lane q
            for (int r = 0; r < 4; ++r) {
                float ar = __shfl(alpha, quad * 4 + r);
                for (int nt = 0; nt < 4; ++nt) o[hf][nt][r] *= ar;
            }

            // P^T -> LDS in PV A-layout: Plds[q][key]
            for (int r = 0; r < 4; ++r) {
                Plds[wave][hf][col][quad * 4 + r]      = (__bf16)v0[r];
                Plds[wave][hf][col][16 + quad * 4 + r] = (__bf16)v1[r];
            }
        }

        // ---- P A-fragments for both halves, then PV (V shared)
        bf16x8 pf[2];
        for (int hf = 0; hf < 2; ++hf) {
            if (kt >= nth[hf]) continue;
            for (int j = 0; j < 8; ++j)
                pf[hf][j] = Plds[wave][hf][col][quad * 8 + j];
        }
        for (int nt = 0; nt < 4; ++nt) {
            bf16x8 bv = ld_bf8(Vb + (size_t)(nt * 16 + col) * SEQ + kb + quad * 8);
            if (kt < nth[0])
                o[0][nt] = __builtin_amdgcn_mfma_f32_16x16x32_bf16(pf[0], bv, o[0][nt], 0, 0, 0);
            o[1][nt] = __builtin_amdgcn_mfma_f32_16x16x32_bf16(pf[1], bv, o[1][nt], 0, 0, 0);
        }
    }

    for (int hf = 0; hf < 2; ++hf) {
        float linv = 1.f / l_i[hf];
        for (int r = 0; r < 4; ++r) {
            float lr = __shfl(linv, quad * 4 + r);
            int qrow = q0h[hf] + quad * 4 + r;
            for (int nt = 0; nt < 4; ++nt)
                O[((size_t)b * SEQ + qrow) * DM + h * 64 + nt * 16 + col] =
                    f2b(o[hf][nt][r] * lr);
        }
    }
}

// ---------------------------------------------------------------------------
extern "C" void kernel_launch(void* const* d_in, const int* in_sizes, int n_in,
                              void* d_out, int out_size, void* d_ws, size_t ws_size,
                              hipStream_t stream) {
    const float* x    = (const float*)d_in[0];   // fp32 inputs (R3->R5 proven)
    const float* Wq   = (const float*)d_in[2];
    const float* Wk   = (const float*)d_in[3];
    const float* Wv   = (const float*)d_in[4];
    const float* Wo   = (const float*)d_in[5];
    const float* cosT = (const float*)d_in[6];
    const float* sinT = (const float*)d_in[7];
    float* out = (float*)d_out;                  // fp32 output (R8 proven)

    // Workspace: 16,777,216 u16 = 32 MiB (R8-proven safe size).
    u16* ws    = (u16*)d_ws;
    u16* qp    = ws;               // (bh,s,d)
    u16* kp    = ws + 4194304;
    u16* vt    = ws + 8388608;     // (bh,d,s); dead after flash
    u16* woT   = ws + 8388608;     // overlays vt, written after flash
    u16* wqkvT = ws + 12582912;    // dead after gemm_qkv
    u16* ao    = ws + 12582912;    // overlays wqkvT

    dim3 blk(256);
    transpose_wqkv<<<dim3(16, 16, 3), blk, 0, stream>>>(Wq, Wk, Wv, wqkvT);
    gemm_qkv<<<dim3(32, 24), blk, 0, stream>>>(x, wqkvT, qp, kp, vt);
    rope_qk<<<dim3(8192), blk, 0, stream>>>(qp, kp, cosT, sinT);
    flash_attn<<<dim3(16, NBH), blk, 0, stream>>>(qp, kp, vt, ao);
    transpose_wo<<<dim3(16, 16), blk, 0, stream>>>(Wo, woT);
    gemm_wo<<<dim3(32, 8), blk, 0, stream>>>(ao, woT, out);
}